// Round 11
// baseline (30.129 us; speedup 1.0000x reference)
//
#include <hip/hip_runtime.h>
#include <math.h>

#define NB 4096
#define ND 128
#define TT 256        // tile size; K = ND = 128 staged whole
#define NT (NB / TT)  // 16 tiles per dimension; grid = 256 = 1 block/CU

typedef __bf16 bf16x8 __attribute__((ext_vector_type(8)));
typedef __bf16 bf16x4 __attribute__((ext_vector_type(4)));
typedef float  f32x4  __attribute__((ext_vector_type(4)));

// ---- pass 1: L2-normalize rows -> bf16; lane0 of block0 zeroes out[0] -------
__global__ __launch_bounds__(256) void rownorm_kernel(
    const float* __restrict__ f, __bf16* __restrict__ fnb, float* __restrict__ out)
{
    if (blockIdx.x == 0 && threadIdx.x == 0) out[0] = 0.f;
    const int t   = blockIdx.x * 256 + threadIdx.x;
    const int row = t >> 5;
    const int c   = (t & 31) << 2;
    float4 v = *reinterpret_cast<const float4*>(f + (size_t)row * ND + c);
    float ss = v.x * v.x + v.y * v.y + v.z * v.z + v.w * v.w;
#pragma unroll
    for (int off = 1; off < 32; off <<= 1) ss += __shfl_xor(ss, off, 64);
    const float inv = 1.0f / fmaxf(sqrtf(ss), 1e-12f);
    bf16x4 o;
    o[0] = (__bf16)(v.x * inv); o[1] = (__bf16)(v.y * inv);
    o[2] = (__bf16)(v.z * inv); o[3] = (__bf16)(v.w * inv);
    *reinterpret_cast<bf16x4*>(fnb + (size_t)row * ND + c) = o;
}

// ---- pass 2: 256x256 LDS-staged sim-tile + MFMA + fused stats ---------------
// R10 body, UNCHANGED. Launched TWICE this round (second into scratch
// partials2) to measure supcon's marginal in-kernel cost via Delta(total).
__global__ __launch_bounds__(1024) void supcon_mfma(
    const __bf16* __restrict__ fn, const int* __restrict__ labels,
    float* __restrict__ partials)
{
    __shared__ __align__(16) __bf16 At[TT * ND];   // 64 KB (i rows)
    __shared__ __align__(16) __bf16 Bt[TT * ND];   // 64 KB (j rows)
    __shared__ float redL[2][TT][3];               // 6 KB

    const int t    = threadIdx.x;
    const int lane = t & 63;
    const int wid  = t >> 6;            // 0..15
    const int wr   = wid >> 1;          // 0..7 : i rows wr*32 .. +32
    const int wc   = wid & 1;           // 0..1 : j cols wc*128 .. +128
    const int bi   = blockIdx.x >> 4;   // i tile 0..15
    const int cs   = blockIdx.x & 15;   // j tile 0..15
    const int lr   = lane & 15;
    const int lk   = lane >> 4;
    const int ib   = bi * TT;
    const int jb   = cs * TT;

    // ---- stage A (i rows) and B (j rows), XOR-swizzled, coalesced source ----
    {
        const __bf16* gA = fn + (size_t)ib * ND;
        const __bf16* gB = fn + (size_t)jb * ND;
#pragma unroll
        for (int i = 0; i < 4; ++i) {
            const int id  = i * 1024 + t;         // chunk 0..4095
            const int row = id >> 4;
            const int c16 = id & 15;
            const int dst = (row * 16 + (c16 ^ (row & 15))) * 8;
            *reinterpret_cast<bf16x8*>(&At[dst]) =
                *reinterpret_cast<const bf16x8*>(gA + row * ND + c16 * 8);
            *reinterpret_cast<bf16x8*>(&Bt[dst]) =
                *reinterpret_cast<const bf16x8*>(gB + row * ND + c16 * 8);
        }
    }

    // my i indices / labels (overlap staging latency)
    int ig[2], labi[2];
#pragma unroll
    for (int it = 0; it < 2; ++it) {
        ig[it]   = ib + wr * 32 + it * 16 + lr;   // D col = lane&15
        labi[it] = labels[ig[it]];
    }

    __syncthreads();

    // preload i-side fragments (MFMA B operand)
    bf16x8 bfr[2][4];
#pragma unroll
    for (int it = 0; it < 2; ++it)
#pragma unroll
        for (int ks = 0; ks < 4; ++ks) {
            const int row = wr * 32 + it * 16 + lr;
            bfr[it][ks] = *reinterpret_cast<const bf16x8*>(
                &At[(row * 16 + ((ks * 4 + lk) ^ lr)) * 8]);
        }

    float es[2] = {}, ps[2] = {}, np[2] = {};

#pragma unroll
    for (int jt = 0; jt < 8; ++jt) {
        // j-side fragments (MFMA A operand)
        bf16x8 af[4];
#pragma unroll
        for (int ks = 0; ks < 4; ++ks) {
            const int row = wc * 128 + jt * 16 + lr;
            af[ks] = *reinterpret_cast<const bf16x8*>(
                &Bt[(row * 16 + ((ks * 4 + lk) ^ lr)) * 8]);
        }
        f32x4 acc[2] = {};
#pragma unroll
        for (int ks = 0; ks < 4; ++ks)
#pragma unroll
            for (int it = 0; it < 2; ++it)
                acc[it] = __builtin_amdgcn_mfma_f32_16x16x32_bf16(
                    af[ks], bfr[it][ks], acc[it], 0, 0, 0);

        // j labels for this 16-tile: contiguous int4 per lk group
        const int jg0 = jb + wc * 128 + jt * 16 + lk * 4;   // D row = lk*4 + r
        const int4 lj4 = *reinterpret_cast<const int4*>(&labels[jg0]);
        const int lj[4] = {lj4.x, lj4.y, lj4.z, lj4.w};

        // epilogue: D[row = j-local = lk*4+r][col = i-local = lr]
#pragma unroll
        for (int it = 0; it < 2; ++it)
#pragma unroll
            for (int r = 0; r < 4; ++r) {
                const int   jgv  = jg0 + r;
                const float s    = acc[it][r];
                const float e    = __expf(s);
                const bool  self = (jgv == ig[it]);
                const bool  pos  = (lj[r] == labi[it]) && !self;
                es[it] += self ? 0.f : e;
                ps[it] += pos ? s : 0.f;
                np[it] += pos ? 1.f : 0.f;
            }
    }

    // cross-lane reduce over the 4 lk-groups only (offsets 16, 32)
#pragma unroll
    for (int off = 16; off < 64; off <<= 1)
#pragma unroll
        for (int it = 0; it < 2; ++it) {
            es[it] += __shfl_xor(es[it], off, 64);
            ps[it] += __shfl_xor(ps[it], off, 64);
            np[it] += __shfl_xor(np[it], off, 64);
        }
    if (lk == 0) {
#pragma unroll
        for (int it = 0; it < 2; ++it) {
            const int rl = wr * 32 + it * 16 + lr;
            redL[wc][rl][0] = es[it];
            redL[wc][rl][1] = ps[it];
            redL[wc][rl][2] = np[it];
        }
    }
    __syncthreads();
    if (t < TT) {   // fold the 2 col-halves; one deterministic writer per (cs,row)
        float* p = partials + ((size_t)cs * NB + ib + t) * 3;
        p[0] = redL[0][t][0] + redL[1][t][0];
        p[1] = redL[0][t][1] + redL[1][t][1];
        p[2] = redL[0][t][2] + redL[1][t][2];
    }
}

// ---- pass 3: per-row loss + block-level reduce + atomic to out --------------
__global__ __launch_bounds__(256) void final_kernel(
    const float* __restrict__ partials, float* __restrict__ out)
{
    const int row = blockIdx.x * 256 + threadIdx.x;
    float es = 0.f, ps = 0.f, np = 0.f;
#pragma unroll
    for (int cs = 0; cs < NT; ++cs) {
        const float* p = partials + ((size_t)cs * NB + row) * 3;
        es += p[0]; ps += p[1]; np += p[2];
    }
    const float lse = logf(es);
    float c = -(ps - np * lse) / ((np + 1e-5f) * (float)NB);
#pragma unroll
    for (int off = 1; off < 64; off <<= 1) c += __shfl_xor(c, off, 64);
    __shared__ float sred[4];
    if ((threadIdx.x & 63) == 0) sred[threadIdx.x >> 6] = c;
    __syncthreads();
    if (threadIdx.x == 0) atomicAdd(out, sred[0] + sred[1] + sred[2] + sred[3]);
}

extern "C" void kernel_launch(void* const* d_in, const int* in_sizes, int n_in,
                              void* d_out, int out_size, void* d_ws, size_t ws_size,
                              hipStream_t stream) {
    const float* features = (const float*)d_in[0];
    const int*   labels   = (const int*)d_in[1];
    float* out = (float*)d_out;

    __bf16* fnb       = (__bf16*)d_ws;                                // 1 MB
    float*  partials  = (float*)((char*)d_ws + (size_t)NB * ND * 2);  // 768 KB
    float*  partials2 = partials + (size_t)NT * NB * 3;               // 768 KB scratch

    rownorm_kernel<<<NB * 32 / 256, 256, 0, stream>>>(features, fnb, out);
    supcon_mfma<<<NT * NT, 1024, 0, stream>>>(fnb, labels, partials);
    supcon_mfma<<<NT * NT, 1024, 0, stream>>>(fnb, labels, partials2);  // A/B probe
    final_kernel<<<NB / 256, 256, 0, stream>>>(partials, out);
}

// Round 12
// 18.608 us; speedup vs baseline: 1.6191x; 1.6191x over previous
//
#include <hip/hip_runtime.h>
#include <math.h>

#define NB 4096
#define ND 128
#define TT 256        // tile size; K = ND = 128 staged whole
#define NT (NB / TT)  // 16 tiles per dimension; grid = 256 = 1 block/CU

typedef __bf16 bf16x8 __attribute__((ext_vector_type(8)));
typedef float  f32x4  __attribute__((ext_vector_type(4)));

// ---- pass 1: fused normalize + 256x256 LDS sim-tile + MFMA + stats ----------
// Each block re-normalizes its own two row-tiles f32->bf16 while staging to
// LDS (deterministic recompute: same per-row op order in every block -> no
// cross-kernel dependency, no fnb buffer, one fewer dispatch boundary).
// LDS layout (16B chunks): (row, c16) -> slot row*16 + (c16 ^ (row&15)).
// Swapped MFMA operands: D col (lane&15) = i index -> stats accumulate
// in-thread; cross-lane reduce = offsets 16/32 only.
// 16 waves (1024 thr): wr = wid>>1 (8 x 32 i-rows), wc = wid&1 (2 x 128 j-cols)
// -> it=2 keeps VGPRs ~110 < 128 cap (R9's it=4 spilled).
__global__ __launch_bounds__(1024) void supcon_mfma(
    const float* __restrict__ f, const int* __restrict__ labels,
    float* __restrict__ partials, float* __restrict__ out)
{
    __shared__ __align__(16) __bf16 At[TT * ND];   // 64 KB (i rows)
    __shared__ __align__(16) __bf16 Bt[TT * ND];   // 64 KB (j rows)
    __shared__ float redL[2][TT][3];               // 6 KB

    const int t    = threadIdx.x;
    const int lane = t & 63;
    const int wid  = t >> 6;            // 0..15
    const int wr   = wid >> 1;          // 0..7 : i rows wr*32 .. +32
    const int wc   = wid & 1;           // 0..1 : j cols wc*128 .. +128
    const int bi   = blockIdx.x >> 4;   // i tile 0..15
    const int cs   = blockIdx.x & 15;   // j tile 0..15
    const int lr   = lane & 15;
    const int lk   = lane >> 4;
    const int ib   = bi * TT;
    const int jb   = cs * TT;

    if (blockIdx.x == 0 && t == 0) out[0] = 0.f;   // target of final's atomics

    // ---- stage + normalize both tiles (f32 -> bf16, XOR-swizzled) -----------
    {
        const int c16  = t & 15;        // 16B-chunk index within row
        const int rloc = t >> 4;        // 0..63
        const float* gA = f + (size_t)ib * ND;
        const float* gB = f + (size_t)jb * ND;
#pragma unroll
        for (int s = 0; s < 2; ++s) {
            const float* g = s ? gB : gA;
            __bf16*      T = s ? Bt : At;
#pragma unroll
            for (int p = 0; p < 4; ++p) {
                const int row = p * 64 + rloc;
                const float4 lo = *reinterpret_cast<const float4*>(g + row * ND + c16 * 8);
                const float4 hi = *reinterpret_cast<const float4*>(g + row * ND + c16 * 8 + 4);
                float ss = lo.x*lo.x + lo.y*lo.y + lo.z*lo.z + lo.w*lo.w
                         + hi.x*hi.x + hi.y*hi.y + hi.z*hi.z + hi.w*hi.w;
#pragma unroll
                for (int off = 1; off < 16; off <<= 1) ss += __shfl_xor(ss, off, 64);
                const float inv = 1.0f / fmaxf(sqrtf(ss), 1e-12f);
                bf16x8 o;
                o[0] = (__bf16)(lo.x * inv); o[1] = (__bf16)(lo.y * inv);
                o[2] = (__bf16)(lo.z * inv); o[3] = (__bf16)(lo.w * inv);
                o[4] = (__bf16)(hi.x * inv); o[5] = (__bf16)(hi.y * inv);
                o[6] = (__bf16)(hi.z * inv); o[7] = (__bf16)(hi.w * inv);
                *reinterpret_cast<bf16x8*>(&T[(row * 16 + (c16 ^ (row & 15))) * 8]) = o;
            }
        }
    }

    // my i indices / labels (overlap staging latency)
    int ig[2], labi[2];
#pragma unroll
    for (int it = 0; it < 2; ++it) {
        ig[it]   = ib + wr * 32 + it * 16 + lr;   // D col = lane&15
        labi[it] = labels[ig[it]];
    }

    __syncthreads();

    // preload i-side fragments (MFMA B operand)
    bf16x8 bfr[2][4];
#pragma unroll
    for (int it = 0; it < 2; ++it)
#pragma unroll
        for (int ks = 0; ks < 4; ++ks) {
            const int row = wr * 32 + it * 16 + lr;
            bfr[it][ks] = *reinterpret_cast<const bf16x8*>(
                &At[(row * 16 + ((ks * 4 + lk) ^ lr)) * 8]);
        }

    float es[2] = {}, ps[2] = {}, np[2] = {};

#pragma unroll
    for (int jt = 0; jt < 8; ++jt) {
        // j-side fragments (MFMA A operand)
        bf16x8 af[4];
#pragma unroll
        for (int ks = 0; ks < 4; ++ks) {
            const int row = wc * 128 + jt * 16 + lr;
            af[ks] = *reinterpret_cast<const bf16x8*>(
                &Bt[(row * 16 + ((ks * 4 + lk) ^ lr)) * 8]);
        }
        f32x4 acc[2] = {};
#pragma unroll
        for (int ks = 0; ks < 4; ++ks)
#pragma unroll
            for (int it = 0; it < 2; ++it)
                acc[it] = __builtin_amdgcn_mfma_f32_16x16x32_bf16(
                    af[ks], bfr[it][ks], acc[it], 0, 0, 0);

        // j labels for this 16-tile: contiguous int4 per lk group
        const int jg0 = jb + wc * 128 + jt * 16 + lk * 4;   // D row = lk*4 + r
        const int4 lj4 = *reinterpret_cast<const int4*>(&labels[jg0]);
        const int lj[4] = {lj4.x, lj4.y, lj4.z, lj4.w};

        // epilogue: D[row = j-local = lk*4+r][col = i-local = lr]
#pragma unroll
        for (int it = 0; it < 2; ++it)
#pragma unroll
            for (int r = 0; r < 4; ++r) {
                const int   jgv  = jg0 + r;
                const float s    = acc[it][r];
                const float e    = __expf(s);
                const bool  self = (jgv == ig[it]);
                const bool  pos  = (lj[r] == labi[it]) && !self;
                es[it] += self ? 0.f : e;
                ps[it] += pos ? s : 0.f;
                np[it] += pos ? 1.f : 0.f;
            }
    }

    // cross-lane reduce over the 4 lk-groups only (offsets 16, 32)
#pragma unroll
    for (int off = 16; off < 64; off <<= 1)
#pragma unroll
        for (int it = 0; it < 2; ++it) {
            es[it] += __shfl_xor(es[it], off, 64);
            ps[it] += __shfl_xor(ps[it], off, 64);
            np[it] += __shfl_xor(np[it], off, 64);
        }
    if (lk == 0) {
#pragma unroll
        for (int it = 0; it < 2; ++it) {
            const int rl = wr * 32 + it * 16 + lr;
            redL[wc][rl][0] = es[it];
            redL[wc][rl][1] = ps[it];
            redL[wc][rl][2] = np[it];
        }
    }
    __syncthreads();
    if (t < TT) {   // fold the 2 col-halves; one deterministic writer per (cs,row)
        float* p = partials + ((size_t)cs * NB + ib + t) * 3;
        p[0] = redL[0][t][0] + redL[1][t][0];
        p[1] = redL[0][t][1] + redL[1][t][1];
        p[2] = redL[0][t][2] + redL[1][t][2];
    }
}

// ---- pass 2: per-row loss + block-level reduce + atomic to out --------------
__global__ __launch_bounds__(256) void final_kernel(
    const float* __restrict__ partials, float* __restrict__ out)
{
    const int row = blockIdx.x * 256 + threadIdx.x;
    float es = 0.f, ps = 0.f, np = 0.f;
#pragma unroll
    for (int cs = 0; cs < NT; ++cs) {
        const float* p = partials + ((size_t)cs * NB + row) * 3;
        es += p[0]; ps += p[1]; np += p[2];
    }
    const float lse = logf(es);
    float c = -(ps - np * lse) / ((np + 1e-5f) * (float)NB);
#pragma unroll
    for (int off = 1; off < 64; off <<= 1) c += __shfl_xor(c, off, 64);
    __shared__ float sred[4];
    if ((threadIdx.x & 63) == 0) sred[threadIdx.x >> 6] = c;
    __syncthreads();
    if (threadIdx.x == 0) atomicAdd(out, sred[0] + sred[1] + sred[2] + sred[3]);
}

extern "C" void kernel_launch(void* const* d_in, const int* in_sizes, int n_in,
                              void* d_out, int out_size, void* d_ws, size_t ws_size,
                              hipStream_t stream) {
    const float* features = (const float*)d_in[0];
    const int*   labels   = (const int*)d_in[1];
    float* out = (float*)d_out;
    float* partials = (float*)d_ws;    // 16*4096*3*4 = 768 KB

    supcon_mfma<<<NT * NT, 1024, 0, stream>>>(features, labels, partials, out);
    final_kernel<<<NB / 256, 256, 0, stream>>>(partials, out);
}